// Round 3
// baseline (249.356 us; speedup 1.0000x reference)
//
#include <hip/hip_runtime.h>

// Laplace transform forward: out[n,i,f] = e[i]*out[n-1,i,f] + decay[i]*inp[n,f]
// T=2048, F=256, N_S=108. float32 in / float32 out.
//
// R5: store-stream locality rewrite of phase C. R4 post-mortem: kernel path
// stuck at ~2.5 TB/s writes while the harness fill does 6.6 TB/s on the same
// buffer. Cause: old phase C had 6912 co-resident wave streams each striding
// 110,592B between 1KB stores -> DRAM row-miss bound. New phase C: one block
// owns ALL 108 taustars x 8 time steps; lane = f4-group, thread carries 27
// register states (fully unrolled -> no scratch); per n the block emits one
// CONTIGUOUS 108KB n-slice, so each block writes one sequential 864KB region.
// 256 blocks = 1/CU. Exact entering state from ws at 32-boundaries (phases
// A/B unchanged, 7MB ws); warm 0/8/16/24 exact steps to the 8-boundary.
// Kernel floor: 226.5MB / 6.3TB/s ~= 36us.

#define T_LEN 2048
#define F_DIM 256
#define NS    108      // NTAU + 2*K = 100 + 8
#define KPAD  4
#define CH    32            // A/B chunk
#define NB    (T_LEN / CH)  // 64
#define CHC   8             // phase C slice span
#define NBC   (T_LEN / CHC) // 256 blocks
#define NJ    27            // i-slots per thread (NS/4 waves)

typedef float f32x4 __attribute__((ext_vector_type(4)));

__device__ __forceinline__ void laplace_consts(int i, float& s, float& e, float& decay) {
    const float c   = powf(20.0f, 1.0f / 99.0f) - 1.0f;
    const float tau = powf(1.0f + c, (float)(i - KPAD));
    s     = 4.0f / tau;
    e     = expf(-s);
    decay = (1.0f - e) / s;
}

// ws slot for (chunk b, taustar i, f4-group lane): float4
__device__ __forceinline__ size_t ws_idx(int b, int i, int lane) {
    return (((size_t)b * NS + i) * 64 + lane) * 4;
}

// Phase A: local 32-step scan from zero state -> L_b  (unchanged)
__global__ __launch_bounds__(256) void laplace_local(
    const float* __restrict__ inp,   // (T, F)
    float* __restrict__ ws)          // (NB, NS, 64) float4
{
    const int lane = threadIdx.x & 63;
    const int i    = blockIdx.y * 4 + (threadIdx.x >> 6);
    const int b    = blockIdx.x;

    float s, e, decay;
    laplace_consts(i, s, e, decay);

    const float* ip = inp + lane * 4;
    float t0 = 0.f, t1 = 0.f, t2 = 0.f, t3 = 0.f;

    const int n0 = b * CH;
    #pragma unroll 8
    for (int n = n0; n < n0 + CH; ++n) {
        f32x4 x = *(const f32x4*)(ip + (size_t)n * F_DIM);
        t0 = fmaf(e, t0, decay * x.x);
        t1 = fmaf(e, t1, decay * x.y);
        t2 = fmaf(e, t2, decay * x.z);
        t3 = fmaf(e, t3, decay * x.w);
    }
    f32x4 r; r.x = t0; r.y = t1; r.z = t2; r.w = t3;
    *(f32x4*)(ws + ws_idx(b, i, lane)) = r;
}

// Phase B: in-place combine -> ws[b] = EXACT state entering chunk b (unchanged)
__global__ __launch_bounds__(256) void laplace_combine(
    float* __restrict__ ws)
{
    const int lane = threadIdx.x & 63;
    const int i    = blockIdx.x * 4 + (threadIdx.x >> 6);

    float s, e, decay;
    laplace_consts(i, s, e, decay);
    const float g = expf(-s * (float)CH);   // e^CH

    float S0 = 0.f, S1 = 0.f, S2 = 0.f, S3 = 0.f;
    #pragma unroll 8
    for (int b = 0; b < NB; ++b) {
        f32x4* p = (f32x4*)(ws + ws_idx(b, i, lane));
        f32x4 L = *p;
        f32x4 S; S.x = S0; S.y = S1; S.z = S2; S.w = S3;
        *p = S;
        S0 = fmaf(g, S0, L.x);
        S1 = fmaf(g, S1, L.y);
        S2 = fmaf(g, S2, L.z);
        S3 = fmaf(g, S3, L.w);
    }
}

// Phase C (R5): slice-sequential writer. Block b2 owns n in [8*b2, 8*b2+8),
// ALL 108 i. lane = f4 group; wave w handles i = 4j+w, j=0..26 (27 register
// states per thread). Per n the block writes one contiguous 108KB slice.
__global__ __launch_bounds__(256, 1) void laplace_slice(
    const float* __restrict__ inp,
    const float* __restrict__ ws,
    float* __restrict__ out)         // (T, NS, F)
{
    __shared__ float sE[NS], sD[NS];
    const int tid = threadIdx.x;
    if (tid < NS) {
        float s, e, d;
        laplace_consts(tid, s, e, d);
        sE[tid] = e; sD[tid] = d;
    }
    __syncthreads();

    const int w    = tid >> 6;          // wave 0..3
    const int lane = tid & 63;
    const int f0   = lane * 4;
    const int b2   = blockIdx.x;        // 0..255
    const int n0   = b2 * CHC;
    const int bb   = b2 >> 2;           // enclosing 32-chunk
    const int base = bb * CH;           // warm start (exact state here)

    // per-slot constants and entering state (all static indices -> VGPRs)
    float eR[NJ], dR[NJ];
    f32x4 st[NJ];
    #pragma unroll
    for (int j = 0; j < NJ; ++j) {
        const int i = j * 4 + w;
        eR[j] = sE[i];
        dR[j] = sD[i];
        st[j] = *(const f32x4*)(ws + ws_idx(bb, i, lane));
    }

    const float* ip = inp + f0;

    // warm: advance exactly from the 32-boundary to n0 (0/8/16/24 steps)
    for (int n = base; n < n0; ++n) {
        f32x4 x = *(const f32x4*)(ip + (size_t)n * F_DIM);
        #pragma unroll
        for (int j = 0; j < NJ; ++j) {
            st[j].x = fmaf(eR[j], st[j].x, dR[j] * x.x);
            st[j].y = fmaf(eR[j], st[j].y, dR[j] * x.y);
            st[j].z = fmaf(eR[j], st[j].z, dR[j] * x.z);
            st[j].w = fmaf(eR[j], st[j].w, dR[j] * x.w);
        }
    }

    // main: 8 n-slices, each written contiguously by the whole block
    for (int n = n0; n < n0 + CHC; ++n) {
        f32x4 x = *(const f32x4*)(ip + (size_t)n * F_DIM);
        float* op = out + (size_t)n * (NS * F_DIM) + f0;
        #pragma unroll
        for (int j = 0; j < NJ; ++j) {
            st[j].x = fmaf(eR[j], st[j].x, dR[j] * x.x);
            st[j].y = fmaf(eR[j], st[j].y, dR[j] * x.y);
            st[j].z = fmaf(eR[j], st[j].z, dR[j] * x.z);
            st[j].w = fmaf(eR[j], st[j].w, dR[j] * x.w);
            *(f32x4*)(op + (size_t)(j * 4 + w) * F_DIM) = st[j];
        }
    }
}

// Fallback (approximate warm-up), used only if ws is too small.
#define CHUNK_FB 64
#define WARM_FB  48
__global__ __launch_bounds__(256) void laplace_kernel_fb(
    const float* __restrict__ inp,
    float* __restrict__ out)
{
    const int tid  = threadIdx.x;
    const int lane = tid & 63;
    const int f0   = lane * 4;
    const int i    = blockIdx.y * 4 + (tid >> 6);
    const int n0   = blockIdx.x * CHUNK_FB;

    float s, e, decay;
    laplace_consts(i, s, e, decay);

    const float* ip = inp + f0;
    float t0 = 0.f, t1 = 0.f, t2 = 0.f, t3 = 0.f;

    int nstart = n0 - WARM_FB;
    if (nstart < 0) nstart = 0;
    #pragma unroll 4
    for (int n = nstart; n < n0; ++n) {
        f32x4 x = *(const f32x4*)(ip + (size_t)n * F_DIM);
        t0 = fmaf(e, t0, decay * x.x);
        t1 = fmaf(e, t1, decay * x.y);
        t2 = fmaf(e, t2, decay * x.z);
        t3 = fmaf(e, t3, decay * x.w);
    }
    float* op = out + (size_t)i * F_DIM + f0;
    #pragma unroll 4
    for (int n = n0; n < n0 + CHUNK_FB; ++n) {
        f32x4 x = *(const f32x4*)(ip + (size_t)n * F_DIM);
        t0 = fmaf(e, t0, decay * x.x);
        t1 = fmaf(e, t1, decay * x.y);
        t2 = fmaf(e, t2, decay * x.z);
        t3 = fmaf(e, t3, decay * x.w);
        f32x4 r; r.x = t0; r.y = t1; r.z = t2; r.w = t3;
        *(f32x4*)(op + (size_t)n * (NS * F_DIM)) = r;
    }
}

extern "C" void kernel_launch(void* const* d_in, const int* in_sizes, int n_in,
                              void* d_out, int out_size, void* d_ws, size_t ws_size,
                              hipStream_t stream) {
    const float* inp = (const float*)d_in[0];
    float* out = (float*)d_out;

    const size_t ws_need = (size_t)NB * NS * 64 * 4 * sizeof(float);  // 7,077,888 B

    if (d_ws != nullptr && ws_size >= ws_need) {
        float* ws = (float*)d_ws;
        // A: locals (1728 blocks), B: combine (27 blocks), C: slice writer (256 blocks)
        laplace_local  <<<dim3(NB, NS / 4), 256, 0, stream>>>(inp, ws);
        laplace_combine<<<dim3(NS / 4),     256, 0, stream>>>(ws);
        laplace_slice  <<<dim3(NBC),        256, 0, stream>>>(inp, ws, out);
    } else {
        laplace_kernel_fb<<<dim3(T_LEN / CHUNK_FB, NS / 4), 256, 0, stream>>>(inp, out);
    }
}

// Round 4
// 234.529 us; speedup vs baseline: 1.0632x; 1.0632x over previous
//
#include <hip/hip_runtime.h>

// Laplace transform forward: out[n,i,f] = e[i]*out[n-1,i,f] + decay[i]*inp[n,f]
// T=2048, F=256, N_S=108. float32 in / float32 out.
//
// R6: load-free store burst. R2-R5 post-mortem: all variants (NT/cached,
// strided/contiguous, 1-7 blocks/CU) stuck at ~2.4 TB/s writes while the
// harness fill does 6.5 TB/s. Shared invariant: a global input load inside
// the store loop. Loads and stores share the in-order vmcnt counter, so
// consuming load n waits for all OLDER STORES to ack -> loop advances at
// store-ack latency under HBM pressure. Fix: stage the block's 32KB input
// slice into LDS first (reg-staged, one barrier), then a pure store burst:
// ds_read_b128 (lgkmcnt, separate counter) + FMA + global_store. Zero vmcnt
// waits in the loop.
//
// Phase A: locals L_b for 64 chunks (1728 blocks, 7MB ws writes)
// Phase B: sequential combine (27 blocks) -> exact entering states in ws
// Phase C: burst writer, grid (27 i-groups, 64 chunks), 32KB LDS,
//          5 blocks/CU (LDS-capped), 226.5MB output stream.
// Kernel floor: 226.5MB / 6.3TB/s ~= 36us.

#define T_LEN 2048
#define F_DIM 256
#define NS    108      // NTAU + 2*K = 100 + 8
#define KPAD  4
#define CH    32            // chunk length (A/B/C all use 32)
#define NB    (T_LEN / CH)  // 64

typedef float f32x4 __attribute__((ext_vector_type(4)));

__device__ __forceinline__ void laplace_consts(int i, float& s, float& e, float& decay) {
    const float c   = powf(20.0f, 1.0f / 99.0f) - 1.0f;
    const float tau = powf(1.0f + c, (float)(i - KPAD));
    s     = 4.0f / tau;
    e     = expf(-s);
    decay = (1.0f - e) / s;
}

// ws slot for (chunk b, taustar i, f4-group lane): float4
__device__ __forceinline__ size_t ws_idx(int b, int i, int lane) {
    return (((size_t)b * NS + i) * 64 + lane) * 4;
}

// Phase A: local 32-step scan from zero state -> L_b  (unchanged)
__global__ __launch_bounds__(256) void laplace_local(
    const float* __restrict__ inp,   // (T, F)
    float* __restrict__ ws)          // (NB, NS, 64) float4
{
    const int lane = threadIdx.x & 63;
    const int i    = blockIdx.y * 4 + (threadIdx.x >> 6);
    const int b    = blockIdx.x;

    float s, e, decay;
    laplace_consts(i, s, e, decay);

    const float* ip = inp + lane * 4;
    float t0 = 0.f, t1 = 0.f, t2 = 0.f, t3 = 0.f;

    const int n0 = b * CH;
    #pragma unroll 8
    for (int n = n0; n < n0 + CH; ++n) {
        f32x4 x = *(const f32x4*)(ip + (size_t)n * F_DIM);
        t0 = fmaf(e, t0, decay * x.x);
        t1 = fmaf(e, t1, decay * x.y);
        t2 = fmaf(e, t2, decay * x.z);
        t3 = fmaf(e, t3, decay * x.w);
    }
    f32x4 r; r.x = t0; r.y = t1; r.z = t2; r.w = t3;
    *(f32x4*)(ws + ws_idx(b, i, lane)) = r;
}

// Phase B: in-place combine -> ws[b] = EXACT state entering chunk b (unchanged)
__global__ __launch_bounds__(256) void laplace_combine(
    float* __restrict__ ws)
{
    const int lane = threadIdx.x & 63;
    const int i    = blockIdx.x * 4 + (threadIdx.x >> 6);

    float s, e, decay;
    laplace_consts(i, s, e, decay);
    const float g = expf(-s * (float)CH);   // e^CH

    float S0 = 0.f, S1 = 0.f, S2 = 0.f, S3 = 0.f;
    #pragma unroll 8
    for (int b = 0; b < NB; ++b) {
        f32x4* p = (f32x4*)(ws + ws_idx(b, i, lane));
        f32x4 L = *p;
        f32x4 S; S.x = S0; S.y = S1; S.z = S2; S.w = S3;
        *p = S;
        S0 = fmaf(g, S0, L.x);
        S1 = fmaf(g, S1, L.y);
        S2 = fmaf(g, S2, L.z);
        S3 = fmaf(g, S3, L.w);
    }
}

// Phase C (R6): LDS-staged, load-free store burst.
// Block (ig, b): taustars ig*4..ig*4+3 (one per wave), chunk b.
// Stage 32 rows (1KB each) into LDS, barrier, then 32x {ds_read+FMA+store}.
__global__ __launch_bounds__(256) void laplace_burst(
    const float* __restrict__ inp,
    const float* __restrict__ ws,
    float* __restrict__ out)         // (T, NS, F)
{
    __shared__ float xs[CH][F_DIM];  // 32 KB

    const int tid  = threadIdx.x;
    const int w    = tid >> 6;          // wave 0..3
    const int lane = tid & 63;
    const int f0   = lane * 4;
    const int ig   = blockIdx.x;        // i-group 0..26
    const int b    = blockIdx.y;        // chunk 0..63
    const int i    = ig * 4 + w;
    const int n0   = b * CH;

    float s, e, d;
    laplace_consts(i, s, e, d);

    // --- stage input slice: wave w loads rows w*8 .. w*8+7 (coalesced 1KB/row)
    const float* ip = inp + (size_t)n0 * F_DIM + f0;
    f32x4 v[8];
    #pragma unroll
    for (int r = 0; r < 8; ++r)
        v[r] = *(const f32x4*)(ip + (size_t)(w * 8 + r) * F_DIM);

    // entering state (exact, from phase B)
    f32x4 S = *(const f32x4*)(ws + ws_idx(b, i, lane));

    #pragma unroll
    for (int r = 0; r < 8; ++r)
        *(f32x4*)(&xs[w * 8 + r][f0]) = v[r];
    __syncthreads();

    // --- pure store burst: no global loads => no vmcnt waits in the loop
    float t0 = S.x, t1 = S.y, t2 = S.z, t3 = S.w;
    float* op = out + (size_t)n0 * (NS * F_DIM) + (size_t)i * F_DIM + f0;

    #pragma unroll 8
    for (int n = 0; n < CH; ++n) {
        f32x4 x = *(const f32x4*)(&xs[n][f0]);   // ds_read_b128, lgkmcnt only
        t0 = fmaf(e, t0, d * x.x);
        t1 = fmaf(e, t1, d * x.y);
        t2 = fmaf(e, t2, d * x.z);
        t3 = fmaf(e, t3, d * x.w);
        f32x4 r; r.x = t0; r.y = t1; r.z = t2; r.w = t3;
        *(f32x4*)(op + (size_t)n * (NS * F_DIM)) = r;
    }
}

// Fallback (approximate warm-up), used only if ws is too small.
#define CHUNK_FB 64
#define WARM_FB  48
__global__ __launch_bounds__(256) void laplace_kernel_fb(
    const float* __restrict__ inp,
    float* __restrict__ out)
{
    const int tid  = threadIdx.x;
    const int lane = tid & 63;
    const int f0   = lane * 4;
    const int i    = blockIdx.y * 4 + (tid >> 6);
    const int n0   = blockIdx.x * CHUNK_FB;

    float s, e, decay;
    laplace_consts(i, s, e, decay);

    const float* ip = inp + f0;
    float t0 = 0.f, t1 = 0.f, t2 = 0.f, t3 = 0.f;

    int nstart = n0 - WARM_FB;
    if (nstart < 0) nstart = 0;
    #pragma unroll 4
    for (int n = nstart; n < n0; ++n) {
        f32x4 x = *(const f32x4*)(ip + (size_t)n * F_DIM);
        t0 = fmaf(e, t0, decay * x.x);
        t1 = fmaf(e, t1, decay * x.y);
        t2 = fmaf(e, t2, decay * x.z);
        t3 = fmaf(e, t3, decay * x.w);
    }
    float* op = out + (size_t)i * F_DIM + f0;
    #pragma unroll 4
    for (int n = n0; n < n0 + CHUNK_FB; ++n) {
        f32x4 x = *(const f32x4*)(ip + (size_t)n * F_DIM);
        t0 = fmaf(e, t0, decay * x.x);
        t1 = fmaf(e, t1, decay * x.y);
        t2 = fmaf(e, t2, decay * x.z);
        t3 = fmaf(e, t3, decay * x.w);
        f32x4 r; r.x = t0; r.y = t1; r.z = t2; r.w = t3;
        *(f32x4*)(op + (size_t)n * (NS * F_DIM)) = r;
    }
}

extern "C" void kernel_launch(void* const* d_in, const int* in_sizes, int n_in,
                              void* d_out, int out_size, void* d_ws, size_t ws_size,
                              hipStream_t stream) {
    const float* inp = (const float*)d_in[0];
    float* out = (float*)d_out;

    const size_t ws_need = (size_t)NB * NS * 64 * 4 * sizeof(float);  // 7,077,888 B

    if (d_ws != nullptr && ws_size >= ws_need) {
        float* ws = (float*)d_ws;
        // A: locals (1728 blocks), B: combine (27 blocks), C: burst (1728 blocks)
        laplace_local  <<<dim3(NB, NS / 4), 256, 0, stream>>>(inp, ws);
        laplace_combine<<<dim3(NS / 4),     256, 0, stream>>>(ws);
        laplace_burst  <<<dim3(NS / 4, NB), 256, 0, stream>>>(inp, ws, out);
    } else {
        laplace_kernel_fb<<<dim3(T_LEN / CHUNK_FB, NS / 4), 256, 0, stream>>>(inp, out);
    }
}